// Round 3
// baseline (258.000 us; speedup 1.0000x reference)
//
#include <hip/hip_runtime.h>
#include <hip/hip_bf16.h>
#include <stdint.h>
#include <stddef.h>

#define N_TOT 1024
#define M_TOT 50000
#define M_PAD 50048   // 391 * 128
#define D_TOT 512
#define NC    10

typedef __attribute__((ext_vector_type(8))) __bf16 bf16x8;
typedef __attribute__((ext_vector_type(4))) float f32x4;
typedef __attribute__((ext_vector_type(4))) unsigned int u32x4;

union Frag16 { u32x4 q; bf16x8 b; unsigned short u[8]; };
union Pack8  { u32x4 q; unsigned short u[8]; };

__device__ __forceinline__ unsigned short f2bf(float x) {
  unsigned int u = __float_as_uint(x);
  unsigned int r = (u + 0x7fffu + ((u >> 16) & 1u)) >> 16;
  return (unsigned short)r;
}

__device__ __forceinline__ void gld_lds16(const void* g, void* l) {
  auto gp = (__attribute__((address_space(1))) unsigned int*)(uintptr_t)g;
  auto lp = (__attribute__((address_space(3))) unsigned int*)(uintptr_t)l;
  __builtin_amdgcn_global_load_lds(gp, lp, 16, 0, 0);
}

// Convert exemplars -> bf16 (plain), x -> bf16(x * Sigma_inv); compute
// e_sq[m] = sum S*e^2, x_sq[n] = sum S*x^2. One wave per row (512 elems, 8/lane).
__global__ void prep_rows(const float* __restrict__ e, const float* __restrict__ x,
                          const float* __restrict__ S,
                          unsigned short* __restrict__ eb, unsigned short* __restrict__ xb,
                          float* __restrict__ e_sq, float* __restrict__ x_sq) {
  const int lane = threadIdx.x & 63;
  const int wid  = threadIdx.x >> 6;
  const int row  = blockIdx.x * 4 + wid;   // 0 .. 51071
  const int d0   = lane * 8;

  float4 s0 = *(const float4*)(S + d0);
  float4 s1 = *(const float4*)(S + d0 + 4);
  float ss[8] = {s0.x, s0.y, s0.z, s0.w, s1.x, s1.y, s1.z, s1.w};

  float acc = 0.f;
  Pack8 o;

  if (row < M_PAD) {
    if (row < M_TOT) {
      const float* src = e + (size_t)row * D_TOT + d0;
      float4 v0 = *(const float4*)src;
      float4 v1 = *(const float4*)(src + 4);
      float vv[8] = {v0.x, v0.y, v0.z, v0.w, v1.x, v1.y, v1.z, v1.w};
      #pragma unroll
      for (int j = 0; j < 8; ++j) { acc += ss[j] * vv[j] * vv[j]; o.u[j] = f2bf(vv[j]); }
    } else {
      #pragma unroll
      for (int j = 0; j < 8; ++j) o.u[j] = 0;
      acc = 0.f;
    }
    *(u32x4*)(eb + (size_t)row * D_TOT + d0) = o.q;
    #pragma unroll
    for (int off = 32; off; off >>= 1) acc += __shfl_down(acc, off);
    if (lane == 0) e_sq[row] = (row < M_TOT) ? acc : 1e30f;  // pad rows: exp(-1e30)=0
  } else {
    const int xr = row - M_PAD;  // 0..1023
    const float* src = x + (size_t)xr * D_TOT + d0;
    float4 v0 = *(const float4*)src;
    float4 v1 = *(const float4*)(src + 4);
    float vv[8] = {v0.x, v0.y, v0.z, v0.w, v1.x, v1.y, v1.z, v1.w};
    #pragma unroll
    for (int j = 0; j < 8; ++j) {
      float w = ss[j] * vv[j];
      acc += w * vv[j];             // S * x^2
      o.u[j] = f2bf(w);             // bf16(x * S)
    }
    *(u32x4*)(xb + (size_t)xr * D_TOT + d0) = o.q;
    #pragma unroll
    for (int off = 32; off; off >>= 1) acc += __shfl_down(acc, off);
    if (lane == 0) x_sq[xr] = acc;
  }
}

__global__ void zero_f32(float* __restrict__ p, int n) {
  int i = blockIdx.x * 256 + threadIdx.x;
  if (i < n) p[i] = 0.f;
}

// 128x128 tile, 4 waves (2x2), 16x16x32 bf16 MFMA, K=512 in 16 steps of 32.
// Fused epilogue: attention = exp(-beta*(x_sq + e_sq - 2*cross)), per-class
// LDS reduction, then global atomicAdd of nonzero partials into logits[N][10].
__launch_bounds__(256)
__global__ void gemm_fused(const unsigned short* __restrict__ xb,
                           const unsigned short* __restrict__ eb,
                           const float* __restrict__ x_sq, const float* __restrict__ e_sq,
                           const int* __restrict__ labels,
                           const float* __restrict__ betap,
                           float* __restrict__ logits) {
  __shared__ unsigned short As[128 * 32];  // 8 KB
  __shared__ unsigned short Bs[128 * 32];  // 8 KB
  __shared__ float cls[128 * NC];          // 5 KB

  const int tid  = threadIdx.x;
  const int lane = tid & 63;
  const int wid  = tid >> 6;
  const int wr   = wid >> 1, wc = wid & 1;   // 2x2 waves, each owns 64x64
  const int mt   = blockIdx.x;               // 0..390
  const int nt   = blockIdx.y;               // 0..7

  // staging: chunk c covers tile row c>>2, ushort cols (c&3)*8 .. +7
  const int rA0   = tid >> 2;
  const int colu0 = (tid & 3) * 8;
  const unsigned short* gA0 = xb + (size_t)(nt * 128 + rA0) * D_TOT + colu0;
  const unsigned short* gA1 = gA0 + (size_t)64 * D_TOT;
  const unsigned short* gB0 = eb + (size_t)(mt * 128 + rA0) * D_TOT + colu0;
  const unsigned short* gB1 = gB0 + (size_t)64 * D_TOT;
  unsigned short* lA0 = As + tid * 8;
  unsigned short* lA1 = As + (tid + 256) * 8;
  unsigned short* lB0 = Bs + tid * 8;
  unsigned short* lB1 = Bs + (tid + 256) * 8;

  const f32x4 vzero = {0.f, 0.f, 0.f, 0.f};
  f32x4 acc[4][4];
  #pragma unroll
  for (int i = 0; i < 4; ++i)
    #pragma unroll
    for (int j = 0; j < 4; ++j) acc[i][j] = vzero;

  const int arow = wr * 64 + (lane & 15);
  const int brow = wc * 64 + (lane & 15);
  const int koff = (lane >> 4) * 8;

  for (int ks = 0; ks < 16; ++ks) {
    const int k0 = ks * 32;
    __syncthreads();                       // prev compute done before overwrite
    gld_lds16(gA0 + k0, lA0);
    gld_lds16(gA1 + k0, lA1);
    gld_lds16(gB0 + k0, lB0);
    gld_lds16(gB1 + k0, lB1);
    __syncthreads();                       // vmcnt(0) drain + barrier

    Frag16 fa[4], fb[4];
    #pragma unroll
    for (int i = 0; i < 4; ++i) fa[i].q = *(const u32x4*)(As + (arow + i * 16) * 32 + koff);
    #pragma unroll
    for (int j = 0; j < 4; ++j) fb[j].q = *(const u32x4*)(Bs + (brow + j * 16) * 32 + koff);
    #pragma unroll
    for (int i = 0; i < 4; ++i)
      #pragma unroll
      for (int j = 0; j < 4; ++j)
        acc[i][j] = __builtin_amdgcn_mfma_f32_16x16x32_bf16(fa[i].b, fb[j].b, acc[i][j], 0, 0, 0);
  }

  // ---- epilogue ----
  __syncthreads();
  for (int t = tid; t < 128 * NC; t += 256) cls[t] = 0.f;
  __syncthreads();

  const float beta = betap[0];
  const int mbase = mt * 128 + wc * 64 + (lane & 15);
  int   lab[4]; float esq[4]; bool mv[4];
  #pragma unroll
  for (int j = 0; j < 4; ++j) {
    const int m = mbase + j * 16;
    mv[j]  = (m < M_TOT);
    esq[j] = e_sq[m];
    lab[j] = mv[j] ? labels[m] : 0;
  }

  #pragma unroll
  for (int i = 0; i < 4; ++i) {
    #pragma unroll
    for (int r = 0; r < 4; ++r) {
      const int nloc = wr * 64 + i * 16 + (lane >> 4) * 4 + r;  // C: row=(lane>>4)*4+reg
      const float xs = x_sq[nt * 128 + nloc];
      #pragma unroll
      for (int j = 0; j < 4; ++j) {
        if (!mv[j]) continue;
        const float dist = xs + esq[j] - 2.0f * acc[i][j][r];
        const float a = __expf(-beta * dist);
        if (a != 0.0f) atomicAdd(&cls[nloc * NC + lab[j]], a);  // adding 0 is identity
      }
    }
  }
  __syncthreads();
  for (int t = tid; t < 128 * NC; t += 256) {
    const float v = cls[t];
    if (v != 0.0f) atomicAdd(&logits[(size_t)(nt * 128 + (t / NC)) * NC + (t % NC)], v);
  }
}

// Output dtype is FLOAT32 (reference returns f32 softmax) — write float*.
__global__ void softmax_out(const float* __restrict__ logits,
                            const float* __restrict__ gammap,
                            float* __restrict__ out) {
  const int n = blockIdx.x * blockDim.x + threadIdx.x;
  if (n >= N_TOT) return;
  const float g = gammap[0];
  float v[NC], mx = -3.4e38f;
  #pragma unroll
  for (int c = 0; c < NC; ++c) { v[c] = g * logits[n * NC + c]; mx = fmaxf(mx, v[c]); }
  float s = 0.f;
  #pragma unroll
  for (int c = 0; c < NC; ++c) { v[c] = __expf(v[c] - mx); s += v[c]; }
  const float inv = 1.0f / s;
  #pragma unroll
  for (int c = 0; c < NC; ++c) out[n * NC + c] = v[c] * inv;
}

extern "C" void kernel_launch(void* const* d_in, const int* in_sizes, int n_in,
                              void* d_out, int out_size, void* d_ws, size_t ws_size,
                              hipStream_t stream) {
  const float* x      = (const float*)d_in[0];
  const float* e      = (const float*)d_in[1];
  const int*   labels = (const int*)d_in[2];
  const float* S      = (const float*)d_in[3];
  const float* beta   = (const float*)d_in[4];
  const float* gamma  = (const float*)d_in[5];

  char* ws = (char*)d_ws;
  unsigned short* eb     = (unsigned short*)(ws);              // 50048*512*2 = 51,249,152
  unsigned short* xb     = (unsigned short*)(ws + 51249152);   // 1024*512*2  =  1,048,576
  float*          e_sq   = (float*)(ws + 52297728);            // 50048*4     =    200,192
  float*          x_sq   = (float*)(ws + 52497920);            // 1024*4      =      4,096
  float*          logits = (float*)(ws + 52502016);            // 1024*10*4   =     40,960
  // total ws use: 52,542,976 bytes (~50.1 MiB)

  hipLaunchKernelGGL(prep_rows, dim3((M_PAD + N_TOT) / 4), dim3(256), 0, stream,
                     e, x, S, eb, xb, e_sq, x_sq);
  hipLaunchKernelGGL(zero_f32, dim3(40), dim3(256), 0, stream, logits, N_TOT * NC);
  hipLaunchKernelGGL(gemm_fused, dim3(391, 8), dim3(256), 0, stream,
                     xb, eb, x_sq, e_sq, labels, beta, logits);
  hipLaunchKernelGGL(softmax_out, dim3(4), dim3(256), 0, stream,
                     logits, gamma, (float*)d_out);
}

// Round 6
// 247.920 us; speedup vs baseline: 1.0407x; 1.0407x over previous
//
#include <hip/hip_runtime.h>
#include <hip/hip_bf16.h>
#include <stdint.h>
#include <stddef.h>

#define N_TOT 1024
#define M_TOT 50000
#define M_PAD 50048   // 391 * 128
#define D_TOT 512
#define NC    10

typedef __attribute__((ext_vector_type(8))) __bf16 bf16x8;
typedef __attribute__((ext_vector_type(4))) float f32x4;
typedef __attribute__((ext_vector_type(4))) unsigned int u32x4;

union Frag16 { u32x4 q; bf16x8 b; unsigned short u[8]; };
union Pack8  { u32x4 q; unsigned short u[8]; };

__device__ __forceinline__ unsigned short f2bf(float x) {
  unsigned int u = __float_as_uint(x);
  unsigned int r = (u + 0x7fffu + ((u >> 16) & 1u)) >> 16;
  return (unsigned short)r;
}

__device__ __forceinline__ void gld_lds16(const void* g, void* l) {
  auto gp = (__attribute__((address_space(1))) unsigned int*)(uintptr_t)g;
  auto lp = (__attribute__((address_space(3))) unsigned int*)(uintptr_t)l;
  __builtin_amdgcn_global_load_lds(gp, lp, 16, 0, 0);
}

// Convert exemplars -> bf16 (plain), x -> bf16(x * Sigma_inv); compute
// e_sq[m] = sum S*e^2, x_sq[n] = sum S*x^2. One wave per row (512 elems, 8/lane).
__global__ void prep_rows(const float* __restrict__ e, const float* __restrict__ x,
                          const float* __restrict__ S,
                          unsigned short* __restrict__ eb, unsigned short* __restrict__ xb,
                          float* __restrict__ e_sq, float* __restrict__ x_sq) {
  const int lane = threadIdx.x & 63;
  const int wid  = threadIdx.x >> 6;
  const int row  = blockIdx.x * 4 + wid;   // 0 .. 51071
  const int d0   = lane * 8;

  float4 s0 = *(const float4*)(S + d0);
  float4 s1 = *(const float4*)(S + d0 + 4);
  float ss[8] = {s0.x, s0.y, s0.z, s0.w, s1.x, s1.y, s1.z, s1.w};

  float acc = 0.f;
  Pack8 o;

  if (row < M_PAD) {
    if (row < M_TOT) {
      const float* src = e + (size_t)row * D_TOT + d0;
      float4 v0 = *(const float4*)src;
      float4 v1 = *(const float4*)(src + 4);
      float vv[8] = {v0.x, v0.y, v0.z, v0.w, v1.x, v1.y, v1.z, v1.w};
      #pragma unroll
      for (int j = 0; j < 8; ++j) { acc += ss[j] * vv[j] * vv[j]; o.u[j] = f2bf(vv[j]); }
    } else {
      #pragma unroll
      for (int j = 0; j < 8; ++j) o.u[j] = 0;
      acc = 0.f;
    }
    *(u32x4*)(eb + (size_t)row * D_TOT + d0) = o.q;
    #pragma unroll
    for (int off = 32; off; off >>= 1) acc += __shfl_down(acc, off);
    if (lane == 0) e_sq[row] = (row < M_TOT) ? acc : 1e30f;  // pad rows: exp(-1e30)=0
  } else {
    const int xr = row - M_PAD;  // 0..1023
    const float* src = x + (size_t)xr * D_TOT + d0;
    float4 v0 = *(const float4*)src;
    float4 v1 = *(const float4*)(src + 4);
    float vv[8] = {v0.x, v0.y, v0.z, v0.w, v1.x, v1.y, v1.z, v1.w};
    #pragma unroll
    for (int j = 0; j < 8; ++j) {
      float w = ss[j] * vv[j];
      acc += w * vv[j];             // S * x^2
      o.u[j] = f2bf(w);             // bf16(x * S)
    }
    *(u32x4*)(xb + (size_t)xr * D_TOT + d0) = o.q;
    #pragma unroll
    for (int off = 32; off; off >>= 1) acc += __shfl_down(acc, off);
    if (lane == 0) x_sq[xr] = acc;
  }
}

__global__ void zero_f32(float* __restrict__ p, int n) {
  int i = blockIdx.x * 256 + threadIdx.x;
  if (i < n) p[i] = 0.f;
}

// 128x128 tile, 4 waves (2x2), 16x16x32 bf16 MFMA, K=512 in 16 steps of 32.
// v2: double-buffered LDS prefetch with counted vmcnt(4) — stage(t+1) issued
// before compute(t), loads fly across the MFMA phase (T3/T4-min structure).
// Grid is nt-fastest so the 8 blocks sharing one eb panel run ~concurrently.
__launch_bounds__(256)
__global__ void gemm_fused(const unsigned short* __restrict__ xb,
                           const unsigned short* __restrict__ eb,
                           const float* __restrict__ x_sq, const float* __restrict__ e_sq,
                           const int* __restrict__ labels,
                           const float* __restrict__ betap,
                           float* __restrict__ logits) {
  __shared__ unsigned short As[2][128 * 32];  // 2 x 8 KB
  __shared__ unsigned short Bs[2][128 * 32];  // 2 x 8 KB
  __shared__ float cls[128 * NC];             // 5 KB

  const int tid  = threadIdx.x;
  const int lane = tid & 63;
  const int wid  = tid >> 6;
  const int wr   = wid >> 1, wc = wid & 1;   // 2x2 waves, each owns 64x64
  const int nt   = blockIdx.x;               // 0..7   (fastest -> B-panel locality)
  const int mt   = blockIdx.y;               // 0..390

  // Staging: 512 16B-chunks per tile; chunk c -> (row=c>>2, u=c&3).
  // Wave w instr j covers chunks w*128 + j*64 + lane (lane-linear LDS dest).
  const int cA0 = wid * 128 + lane;
  const int cA1 = cA0 + 64;
  const unsigned short* gA0 = xb + (size_t)(nt * 128 + (cA0 >> 2)) * D_TOT + (cA0 & 3) * 8;
  const unsigned short* gA1 = xb + (size_t)(nt * 128 + (cA1 >> 2)) * D_TOT + (cA1 & 3) * 8;
  const unsigned short* gB0 = eb + (size_t)(mt * 128 + (cA0 >> 2)) * D_TOT + (cA0 & 3) * 8;
  const unsigned short* gB1 = eb + (size_t)(mt * 128 + (cA1 >> 2)) * D_TOT + (cA1 & 3) * 8;

  const f32x4 vzero = {0.f, 0.f, 0.f, 0.f};
  f32x4 acc[4][4];
  #pragma unroll
  for (int i = 0; i < 4; ++i)
    #pragma unroll
    for (int j = 0; j < 4; ++j) acc[i][j] = vzero;

  const int arow = wr * 64 + (lane & 15);
  const int brow = wc * 64 + (lane & 15);
  const int koff = (lane >> 4) * 8;

  // NOTE: macro params named BUF/K0 — a param named 'b' captures the union
  // member access fa[i].b (round-5 compile failure).
  #define STAGE(BUF, K0)                                    \
    do {                                                    \
      gld_lds16(gA0 + (K0), &As[(BUF)][cA0 * 8]);           \
      gld_lds16(gA1 + (K0), &As[(BUF)][cA1 * 8]);           \
      gld_lds16(gB0 + (K0), &Bs[(BUF)][cA0 * 8]);           \
      gld_lds16(gB1 + (K0), &Bs[(BUF)][cA1 * 8]);           \
    } while (0)

  #define COMPUTE(BUF)                                                            \
    do {                                                                          \
      Frag16 fa[4], fb[4];                                                        \
      _Pragma("unroll")                                                           \
      for (int i = 0; i < 4; ++i)                                                 \
        fa[i].q = *(const u32x4*)(&As[(BUF)][(arow + i * 16) * 32 + koff]);       \
      _Pragma("unroll")                                                           \
      for (int j = 0; j < 4; ++j)                                                 \
        fb[j].q = *(const u32x4*)(&Bs[(BUF)][(brow + j * 16) * 32 + koff]);       \
      _Pragma("unroll")                                                           \
      for (int i = 0; i < 4; ++i)                                                 \
        _Pragma("unroll")                                                         \
        for (int j = 0; j < 4; ++j)                                               \
          acc[i][j] = __builtin_amdgcn_mfma_f32_16x16x32_bf16(fa[i].b, fb[j].b,   \
                                                              acc[i][j], 0, 0, 0);\
    } while (0)

  // ---- pipelined K-loop: 16 steps of BK=32 ----
  STAGE(0, 0);
  #pragma unroll 2
  for (int ks = 0; ks < 15; ++ks) {
    const int cur = ks & 1;
    STAGE(cur ^ 1, (ks + 1) * 32);                       // prefetch next tile
    asm volatile("s_waitcnt vmcnt(4)" ::: "memory");     // my stage(ks) landed
    __builtin_amdgcn_s_barrier();                        // everyone's landed
    asm volatile("" ::: "memory");
    COMPUTE(cur);
    asm volatile("s_waitcnt lgkmcnt(0)" ::: "memory");   // my ds_reads complete
    __builtin_amdgcn_sched_barrier(0);
    __builtin_amdgcn_s_barrier();                        // safe to overwrite buf
  }
  asm volatile("s_waitcnt vmcnt(0)" ::: "memory");
  __builtin_amdgcn_s_barrier();
  asm volatile("" ::: "memory");
  COMPUTE(1);
  #undef STAGE
  #undef COMPUTE

  // ---- epilogue ----
  __syncthreads();
  for (int t = tid; t < 128 * NC; t += 256) cls[t] = 0.f;
  __syncthreads();

  const float beta = betap[0];
  const int mbase = mt * 128 + wc * 64 + (lane & 15);
  int   lab[4]; float esq[4]; bool mv[4];
  #pragma unroll
  for (int j = 0; j < 4; ++j) {
    const int m = mbase + j * 16;
    mv[j]  = (m < M_TOT);
    esq[j] = e_sq[m];
    lab[j] = mv[j] ? labels[m] : 0;
  }

  #pragma unroll
  for (int i = 0; i < 4; ++i) {
    #pragma unroll
    for (int r = 0; r < 4; ++r) {
      const int nloc = wr * 64 + i * 16 + (lane >> 4) * 4 + r;  // C: row=(lane>>4)*4+reg
      const float xs = x_sq[nt * 128 + nloc];
      #pragma unroll
      for (int j = 0; j < 4; ++j) {
        if (!mv[j]) continue;
        const float dist = xs + esq[j] - 2.0f * acc[i][j][r];
        const float a = __expf(-beta * dist);
        if (a != 0.0f) atomicAdd(&cls[nloc * NC + lab[j]], a);  // adding 0 is identity
      }
    }
  }
  __syncthreads();
  for (int t = tid; t < 128 * NC; t += 256) {
    const float v = cls[t];
    if (v != 0.0f) atomicAdd(&logits[(size_t)(nt * 128 + (t / NC)) * NC + (t % NC)], v);
  }
}

// Output dtype is FLOAT32 (reference returns f32 softmax) — write float*.
__global__ void softmax_out(const float* __restrict__ logits,
                            const float* __restrict__ gammap,
                            float* __restrict__ out) {
  const int n = blockIdx.x * blockDim.x + threadIdx.x;
  if (n >= N_TOT) return;
  const float g = gammap[0];
  float v[NC], mx = -3.4e38f;
  #pragma unroll
  for (int c = 0; c < NC; ++c) { v[c] = g * logits[n * NC + c]; mx = fmaxf(mx, v[c]); }
  float s = 0.f;
  #pragma unroll
  for (int c = 0; c < NC; ++c) { v[c] = __expf(v[c] - mx); s += v[c]; }
  const float inv = 1.0f / s;
  #pragma unroll
  for (int c = 0; c < NC; ++c) out[n * NC + c] = v[c] * inv;
}

extern "C" void kernel_launch(void* const* d_in, const int* in_sizes, int n_in,
                              void* d_out, int out_size, void* d_ws, size_t ws_size,
                              hipStream_t stream) {
  const float* x      = (const float*)d_in[0];
  const float* e      = (const float*)d_in[1];
  const int*   labels = (const int*)d_in[2];
  const float* S      = (const float*)d_in[3];
  const float* beta   = (const float*)d_in[4];
  const float* gamma  = (const float*)d_in[5];

  char* ws = (char*)d_ws;
  unsigned short* eb     = (unsigned short*)(ws);              // 50048*512*2 = 51,249,152
  unsigned short* xb     = (unsigned short*)(ws + 51249152);   // 1024*512*2  =  1,048,576
  float*          e_sq   = (float*)(ws + 52297728);            // 50048*4     =    200,192
  float*          x_sq   = (float*)(ws + 52497920);            // 1024*4      =      4,096
  float*          logits = (float*)(ws + 52502016);            // 1024*10*4   =     40,960
  // total ws use: 52,542,976 bytes (~50.1 MiB)

  hipLaunchKernelGGL(prep_rows, dim3((M_PAD + N_TOT) / 4), dim3(256), 0, stream,
                     e, x, S, eb, xb, e_sq, x_sq);
  hipLaunchKernelGGL(zero_f32, dim3(40), dim3(256), 0, stream, logits, N_TOT * NC);
  hipLaunchKernelGGL(gemm_fused, dim3(8, 391), dim3(256), 0, stream,
                     xb, eb, x_sq, e_sq, labels, beta, logits);
  hipLaunchKernelGGL(softmax_out, dim3(4), dim3(256), 0, stream,
                     logits, gamma, (float*)d_out);
}